// Round 1
// baseline (399.173 us; speedup 1.0000x reference)
//
#include <hip/hip_runtime.h>

#define S_LEN 1024
#define DH 64
#define NBH 32
#define CROWS 1920                   // 1024+512+256+128 coarse rows
#define HEAD_K (CROWS * DH)          // 122880 elements per head
#define NCHUNK (HEAD_K / 8)          // 15360 16-byte fragment chunks per head
#define ATTN_OFF (NBH * S_LEN * DH)  // start of combined_attention in d_out
#define PSTR 1928                    // LDS probs row stride (bf16 elems, padded)

typedef __attribute__((ext_vector_type(8))) short bf8_t;
typedef __attribute__((ext_vector_type(4))) float f32x4_t;

__device__ __forceinline__ unsigned short f2bf(float x) {
  unsigned u = __float_as_uint(x);
  u += 0x7fffu + ((u >> 16) & 1u);
  return (unsigned short)(u >> 16);
}
__device__ __forceinline__ float bf2f(unsigned short h) {
  return __uint_as_float(((unsigned)h) << 16);
}

// ---------------------------------------------------------------------------
// PREP: pool K -> project -> pack projB; pool V (with +-2 halo) -> 3-point
// stencil (U^T U is tridiagonal) -> pack mpvB. No pv global round-trip.
// Block = (bh, scale-tile of 64 coarse rows). LDS ~53 KB -> 3 blocks/CU.
// ---------------------------------------------------------------------------
__global__ __launch_bounds__(256, 3) void prep_kernel(
    const float* __restrict__ key, const float* __restrict__ value,
    const float* __restrict__ W, const float* __restrict__ b,
    unsigned short* __restrict__ projB, unsigned short* __restrict__ mpvB)
{
  __shared__ __align__(16) float Wl[64 * 64];
  __shared__ __align__(16) float pkv[68 * 68];  // K pool (rows 0..63), then V pool (68 rows)
  __shared__ __align__(16) float prL[64 * 68];
  __shared__ float coefs[64 * 4];               // c-1, c0, c+1 per local coarse row
  const int t = threadIdx.x;
  const int bid = blockIdx.x;
  const int bh = bid / 30;
  const int tt = bid % 30;
  int si, jt;
  if (tt < 16)      { si = 0; jt = tt; }
  else if (tt < 24) { si = 1; jt = tt - 16; }
  else if (tt < 28) { si = 2; jt = tt - 24; }
  else              { si = 3; jt = tt - 28; }
  const int s = 1 << si;
  const int L = 1024 >> si;
  const int off = (si == 0) ? 0 : (si == 1) ? 1024 : (si == 2) ? 1536 : 1792;
  const int j0 = jt << 6;
  const float invs = 1.0f / (float)s;

  // stage W[si] (stride 64, broadcast-read later)
  for (int i = t; i < 1024; i += 256)
    *(float4*)&Wl[i * 4] = *(const float4*)&W[si * 4096 + i * 4];

  // pool K rows j0..j0+63 (float4-vectorized)
  const float* Kp = key + bh * (S_LEN * DH);
  for (int i = t; i < 1024; i += 256) {
    const int j = i >> 4, d4 = (i & 15) << 2;
    const float* src = Kp + (j0 + j) * s * DH + d4;
    float4 a = {0.f, 0.f, 0.f, 0.f};
    for (int f = 0; f < s; f++) {
      const float4 kv = *(const float4*)(src + f * DH);
      a.x += kv.x; a.y += kv.y; a.z += kv.z; a.w += kv.w;
    }
    a.x *= invs; a.y *= invs; a.z *= invs; a.w *= invs;
    *(float4*)&pkv[j * 68 + d4] = a;
  }

  // tridiagonal stencil coefficients of M = U^T U for this block's 64 rows
  if (t < 64) {
    const int j = j0 + t;
    float cm = 0.f, cc = 0.f, cp = 0.f;
    const int klo = max(0, (j - 1) * s);
    const int khi = min(S_LEN - 1, (j + 2) * s);
    for (int kf = klo; kf <= khi; kf++) {
      float srcp = ((float)kf + 0.5f) * invs - 0.5f;
      srcp = fminf(fmaxf(srcp, 0.f), (float)(L - 1));
      const int i0 = (int)floorf(srcp);
      const int i1 = min(i0 + 1, L - 1);
      const float w = srcp - (float)i0;
      float u = 0.f;
      if (i0 == j) u += 1.f - w;
      if (i1 == j) u += w;
      if (u != 0.f) {
        const float g0 = u * (1.f - w), g1 = u * w;
        if (i0 == j) cc += g0; else cm += g0;   // i0 in {j-1, j}
        if (i1 == j) cc += g1; else cp += g1;   // i1 in {j, j+1}
      }
    }
    coefs[t * 4 + 0] = cm; coefs[t * 4 + 1] = cc; coefs[t * 4 + 2] = cp;
  }
  __syncthreads();

  // register-blocked projection: prL = pk @ W^T + b
  {
    const int j  = t & 63;
    const int e0 = (t >> 6) << 4;
    float acc[16];
    #pragma unroll
    for (int ee = 0; ee < 16; ee++) acc[ee] = b[si * 64 + e0 + ee];
    #pragma unroll
    for (int dq = 0; dq < 16; dq++) {
      const float4 p4 = *(const float4*)&pkv[j * 68 + dq * 4];
      #pragma unroll
      for (int ee = 0; ee < 16; ee++) {
        const float4 w4 = *(const float4*)&Wl[(e0 + ee) * 64 + dq * 4];
        acc[ee] += p4.x * w4.x + p4.y * w4.y + p4.z * w4.z + p4.w * w4.w;
      }
    }
    #pragma unroll
    for (int ee = 0; ee < 16; ee++) prL[j * 68 + e0 + ee] = acc[ee];
  }
  __syncthreads();   // prL ready; pkv dead -> reuse for pooled V

  // pool V rows j0-2 .. j0+65 (clamped) into pkv[68 rows]
  const float* Vp = value + bh * (S_LEN * DH);
  for (int i = t; i < 1088; i += 256) {
    const int hj = i >> 4, d4 = (i & 15) << 2;
    const int jg = min(max(j0 - 2 + hj, 0), L - 1);
    const float* src = Vp + jg * s * DH + d4;
    float4 a = {0.f, 0.f, 0.f, 0.f};
    for (int f = 0; f < s; f++) {
      const float4 vv = *(const float4*)(src + f * DH);
      a.x += vv.x; a.y += vv.y; a.z += vv.z; a.w += vv.w;
    }
    a.x *= invs; a.y *= invs; a.z *= invs; a.w *= invs;
    *(float4*)&pkv[hj * 68 + d4] = a;
  }

  // pack projB from prL (reads prL only; runs alongside V-pooling)
  const int ktg0 = (off + j0) >> 4;
  for (int c = t; c < 512; c += 256) {
    const int ktl = c >> 7;
    const int db  = (c >> 6) & 1;
    const int ln  = c & 63;
    const int kl  = ktl * 16 + (ln & 15);
    const int e0p = db * 32 + ((ln >> 4) & 3) * 8;
    const float4 a  = *(const float4*)&prL[kl * 68 + e0p];
    const float4 c4 = *(const float4*)&prL[kl * 68 + e0p + 4];
    bf8_t v;
    v[0] = (short)f2bf(a.x);  v[1] = (short)f2bf(a.y);
    v[2] = (short)f2bf(a.z);  v[3] = (short)f2bf(a.w);
    v[4] = (short)f2bf(c4.x); v[5] = (short)f2bf(c4.y);
    v[6] = (short)f2bf(c4.z); v[7] = (short)f2bf(c4.w);
    ((bf8_t*)projB)[bh * NCHUNK + ((ktg0 + ktl) * 2 + db) * 64 + ln] = v;
  }
  __syncthreads();   // pooled V ready

  // Mpv = stencil(pooled V), packed directly in MFMA-B frag order
  const int kbg0 = (off + j0) >> 5;
  for (int c = t; c < 512; c += 256) {
    const int kbl = c >> 8;              // 0..1
    const int nt  = (c >> 6) & 3;
    const int ln  = c & 63;
    const int d   = nt * 16 + (ln & 15);
    const int r0  = kbl * 32 + ((ln >> 4) & 3) * 8;
    bf8_t v;
    #pragma unroll
    for (int jj = 0; jj < 8; jj++) {
      const int rl = r0 + jj;
      const float cm = coefs[rl * 4 + 0];
      const float cc = coefs[rl * 4 + 1];
      const float cp = coefs[rl * 4 + 2];
      const float val = cm * pkv[(rl + 1) * 68 + d] +
                        cc * pkv[(rl + 2) * 68 + d] +
                        cp * pkv[(rl + 3) * 68 + d];
      v[jj] = (short)f2bf(val);
    }
    ((bf8_t*)mpvB)[bh * NCHUNK + ((kbg0 + kbl) * 4 + nt) * 64 + ln] = v;
  }
}

// ---------------------------------------------------------------------------
// FUSED: 512 threads (8 waves), 2 blocks/CU -> 4 waves/SIMD.
// P2 keeps UNNORMALIZED exp in LDS; 1/sum folded into P3/P4 via sInv table.
// P3 split across wave pairs (kb 0..31 | kb 32..59), LDS partial reduce.
// P4: per-column interp coefficients hoisted out of the row loop.
// ---------------------------------------------------------------------------
__global__ __launch_bounds__(512, 4) void fused_attn_kernel(
    const float* __restrict__ query, const unsigned short* __restrict__ projB,
    const unsigned short* __restrict__ mpvB, float* __restrict__ out)
{
  __shared__ __align__(16) unsigned short prbf[16 * PSTR];
  __shared__ __align__(16) float pOut[16 * 68];
  __shared__ float sInv[16 * 4];
  const int t    = threadIdx.x;
  const int bh   = blockIdx.x & 31;
  const int qt   = blockIdx.x >> 5;
  const int q0   = qt << 4;
  const int wave = t >> 6;
  const int lane = t & 63;
  const int quad = lane >> 4;
  const int n16  = lane & 15;

  // A-frags: A[m=lane&15][k=quad*8+j], k = d (+32 for second frag)
  bf8_t af0, af1;
  {
    const float* qrow = query + bh * (S_LEN * DH) + (q0 + n16) * DH;
    const float4 a0 = *(const float4*)(qrow + quad * 8);
    const float4 a1 = *(const float4*)(qrow + quad * 8 + 4);
    const float4 a2 = *(const float4*)(qrow + 32 + quad * 8);
    const float4 a3 = *(const float4*)(qrow + 32 + quad * 8 + 4);
    af0[0] = (short)f2bf(a0.x); af0[1] = (short)f2bf(a0.y);
    af0[2] = (short)f2bf(a0.z); af0[3] = (short)f2bf(a0.w);
    af0[4] = (short)f2bf(a1.x); af0[5] = (short)f2bf(a1.y);
    af0[6] = (short)f2bf(a1.z); af0[7] = (short)f2bf(a1.w);
    af1[0] = (short)f2bf(a2.x); af1[1] = (short)f2bf(a2.y);
    af1[2] = (short)f2bf(a2.z); af1[3] = (short)f2bf(a2.w);
    af1[4] = (short)f2bf(a3.x); af1[5] = (short)f2bf(a3.y);
    af1[6] = (short)f2bf(a3.z); af1[7] = (short)f2bf(a3.w);
  }

  // zero the pad columns (safe target for the unclamped i0+1 lerp read)
  if (t < 128) prbf[(t >> 3) * PSTR + 1920 + (t & 7)] = 0;

  // ---- P1: scores via MFMA; bf16 (scaled by 1/sqrt(D)) to LDS ----
  {
    const bf8_t* pB = (const bf8_t*)projB + bh * NCHUNK;
    for (int kt = wave; kt < 120; kt += 8) {
      const bf8_t b0 = pB[(kt * 2 + 0) * 64 + lane];
      const bf8_t b1 = pB[(kt * 2 + 1) * 64 + lane];
      f32x4_t c = {0.f, 0.f, 0.f, 0.f};
      c = __builtin_amdgcn_mfma_f32_16x16x32_bf16(af0, b0, c, 0, 0, 0);
      c = __builtin_amdgcn_mfma_f32_16x16x32_bf16(af1, b1, c, 0, 0, 0);
      const int col = kt * 16 + n16;
      #pragma unroll
      for (int i = 0; i < 4; i++)
        prbf[(quad * 4 + i) * PSTR + col] = f2bf(c[i] * 0.125f);
    }
  }
  __syncthreads();

  // ---- P2: per-row per-scale max + exp (UNNORMALIZED), inv -> sInv ----
  {
    const int rr = t >> 5;
    const int g  = t & 31;
    unsigned short* prr = prbf + rr * PSTR;
    #pragma unroll
    for (int si = 0; si < 4; si++) {
      const int nch = (1024 >> si) >> 3;  // ushort8 chunks
      const int off = (si == 0) ? 0 : (si == 1) ? 1024 : (si == 2) ? 1536 : 1792;
      bf8_t* base = (bf8_t*)(prr + off);
      float m = -1e30f;
      for (int ch = g; ch < nch; ch += 32) {
        const bf8_t u = base[ch];
        #pragma unroll
        for (int e = 0; e < 8; e++) m = fmaxf(m, bf2f((unsigned short)u[e]));
      }
      #pragma unroll
      for (int dlt = 16; dlt >= 1; dlt >>= 1) m = fmaxf(m, __shfl_xor(m, dlt));
      float ssum = 0.f;
      for (int ch = g; ch < nch; ch += 32) {
        bf8_t u = base[ch];
        #pragma unroll
        for (int e = 0; e < 8; e++) {
          const float ev = __expf(bf2f((unsigned short)u[e]) - m);
          ssum += ev;
          u[e] = (short)f2bf(ev);
        }
        base[ch] = u;
      }
      #pragma unroll
      for (int dlt = 16; dlt >= 1; dlt >>= 1) ssum += __shfl_xor(ssum, dlt);
      if (g == 0) sInv[rr * 4 + si] = 1.0f / ssum;
    }
  }
  __syncthreads();

  // ---- P3: out = 0.25 * sum_si inv_si * (e_si @ Mpv_si); split wave pairs ----
  {
    const bf8_t* pM = (const bf8_t*)mpvB + bh * NCHUNK;
    const int half = wave >> 2;
    const int nt   = wave & 3;
    f32x4_t aA = {0.f, 0.f, 0.f, 0.f};
    f32x4_t aB = {0.f, 0.f, 0.f, 0.f};
    f32x4_t aC = {0.f, 0.f, 0.f, 0.f};
    const int kb0 = half ? 32 : 0;
    const int kb1 = half ? 48 : 32;
    for (int kb = kb0; kb < kb1; kb++) {
      const bf8_t a  = *(const bf8_t*)(prbf + n16 * PSTR + kb * 32 + quad * 8);
      const bf8_t bb = pM[(kb * 4 + nt) * 64 + lane];
      aA = __builtin_amdgcn_mfma_f32_16x16x32_bf16(a, bb, aA, 0, 0, 0);
    }
    if (half) {
      for (int kb = 48; kb < 56; kb++) {
        const bf8_t a  = *(const bf8_t*)(prbf + n16 * PSTR + kb * 32 + quad * 8);
        const bf8_t bb = pM[(kb * 4 + nt) * 64 + lane];
        aB = __builtin_amdgcn_mfma_f32_16x16x32_bf16(a, bb, aB, 0, 0, 0);
      }
      for (int kb = 56; kb < 60; kb++) {
        const bf8_t a  = *(const bf8_t*)(prbf + n16 * PSTR + kb * 32 + quad * 8);
        const bf8_t bb = pM[(kb * 4 + nt) * 64 + lane];
        aC = __builtin_amdgcn_mfma_f32_16x16x32_bf16(a, bb, aC, 0, 0, 0);
      }
      #pragma unroll
      for (int i = 0; i < 4; i++) {
        const int row = quad * 4 + i;
        pOut[row * 68 + nt * 16 + n16] = aA[i] * sInv[row * 4 + 1] +
                                         aB[i] * sInv[row * 4 + 2] +
                                         aC[i] * sInv[row * 4 + 3];
      }
    }
    __syncthreads();
    if (!half) {
      float* ob = out + bh * (S_LEN * DH) + q0 * DH;
      #pragma unroll
      for (int i = 0; i < 4; i++) {
        const int row = quad * 4 + i;
        ob[row * DH + nt * 16 + n16] =
            0.25f * (aA[i] * sInv[row * 4 + 0] + pOut[row * 68 + nt * 16 + n16]);
      }
    }
  }

  // ---- P4: combined_attention; column-owner layout, hoisted interp coefs ----
  {
    float* ab = out + ATTN_OFF + (size_t)bh * (S_LEN * S_LEN) + (size_t)q0 * S_LEN;
    const int cq    = t & 255;
    const int rbase = (t >> 8) << 3;
    const int k0    = cq << 2;
    int   iofs[3][4];
    float wgt[3][4];
    #pragma unroll
    for (int si = 1; si < 4; si++) {
      const int   L     = 1024 >> si;
      const int   off2  = (si == 1) ? 1024 : (si == 2) ? 1536 : 1792;
      const float inv_s = (si == 1) ? 0.5f : (si == 2) ? 0.25f : 0.125f;
      #pragma unroll
      for (int kk = 0; kk < 4; kk++) {
        float srcp = ((float)(k0 + kk) + 0.5f) * inv_s - 0.5f;
        srcp = fminf(fmaxf(srcp, 0.f), (float)(L - 1));
        const int i0 = (int)floorf(srcp);
        iofs[si - 1][kk] = off2 + i0;
        wgt[si - 1][kk]  = srcp - (float)i0;
      }
    }
    for (int rr = rbase; rr < rbase + 8; rr++) {
      const unsigned short* p2 = prbf + rr * PSTR;
      const float iv0 = sInv[rr * 4 + 0];
      const float iv1 = sInv[rr * 4 + 1];
      const float iv2 = sInv[rr * 4 + 2];
      const float iv3 = sInv[rr * 4 + 3];
      const ushort4 bs = *(const ushort4*)(p2 + k0);
      float res[4] = {bf2f(bs.x) * iv0, bf2f(bs.y) * iv0,
                      bf2f(bs.z) * iv0, bf2f(bs.w) * iv0};
      #pragma unroll
      for (int si = 1; si < 4; si++) {
        const float ivs = (si == 1) ? iv1 : (si == 2) ? iv2 : iv3;
        #pragma unroll
        for (int kk = 0; kk < 4; kk++) {
          const int   io = iofs[si - 1][kk];
          const float w  = wgt[si - 1][kk];
          const float e0 = bf2f(p2[io]);
          const float e1 = bf2f(p2[io + 1]);
          res[kk] += ivs * (e0 + w * (e1 - e0));
        }
      }
      *(float4*)(ab + rr * 1024 + k0) =
          make_float4(res[0] * 0.25f, res[1] * 0.25f,
                      res[2] * 0.25f, res[3] * 0.25f);
    }
  }
}

// ---------------------------------------------------------------------------
extern "C" void kernel_launch(void* const* d_in, const int* in_sizes, int n_in,
                              void* d_out, int out_size, void* d_ws, size_t ws_size,
                              hipStream_t stream) {
  (void)in_sizes; (void)n_in; (void)out_size; (void)ws_size;
  const float* query = (const float*)d_in[0];
  const float* key   = (const float*)d_in[1];
  const float* value = (const float*)d_in[2];
  const float* W     = (const float*)d_in[3];
  const float* b     = (const float*)d_in[4];
  float* out = (float*)d_out;

  unsigned short* projB = (unsigned short*)d_ws;                 // 7.9 MB bf16
  unsigned short* mpvB  = projB + (size_t)NBH * HEAD_K;          // 7.9 MB bf16

  prep_kernel<<<NBH * 30, 256, 0, stream>>>(key, value, W, b, projB, mpvB);
  fused_attn_kernel<<<NBH * 64, 512, 0, stream>>>(query, projB, mpvB, out);
}